// Round 2
// baseline (1010.611 us; speedup 1.0000x reference)
//
#include <hip/hip_runtime.h>
#include <hip/hip_bf16.h>
#include <stdint.h>

// Problem constants (fixed by setup_inputs)
#define B_  32
#define T_  4096
#define D_  768
#define A_  128
#define BT_ (B_ * T_)          // 131072 tokens
#define LN_EPS 1e-5f

typedef __attribute__((ext_vector_type(8))) short  short8;   // 8 x bf16 (4 VGPRs)
typedef __attribute__((ext_vector_type(4))) float  floatx4;  // MFMA acc

// ---------------- helpers ----------------
__device__ __forceinline__ uint32_t pack_bf16x2(float a, float b) {
    __hip_bfloat162 h = __float22bfloat162_rn(make_float2(a, b));
    union { __hip_bfloat162 h; uint32_t u; } cv; cv.h = h;
    return cv.u;   // low 16 bits = a, high = b
}

__device__ __forceinline__ uint16_t f2bf_rne(float f) {
    union { float f; uint32_t u; } cv; cv.f = f;
    uint32_t u = cv.u;
    return (uint16_t)((u + 0x7FFFu + ((u >> 16) & 1u)) >> 16);
}

__device__ __forceinline__ float bf2f(uint16_t h) {
    union { uint32_t u; float f; } cv; cv.u = ((uint32_t)h) << 16;
    return cv.f;
}

// fast tanh via exp:  tanh(x) = (e^{2x}-1)/(e^{2x}+1)
__device__ __forceinline__ float fast_tanh(float x) {
    float e = __expf(2.f * x);
    return __fdividef(e - 1.f, e + 1.f);
}

// ---------------- kernel 1: Wp -> Wp^T bf16 (tiled transpose) ----------------
// Wp: (3, 768, 128) fp32  ->  wpt: (3, 128, 768) bf16
// grid: (3*24, 4); 32x32 tile per block, coalesced read AND write.
__global__ __launch_bounds__(256)
void k_wp(const float* __restrict__ Wp, uint16_t* __restrict__ wpt) {
    const int sd = blockIdx.x;
    const int s  = sd / 24;
    const int d0 = (sd - s * 24) * 32;
    const int a0 = blockIdx.y * 32;
    const int tid = threadIdx.x;
    const int r = tid >> 5, c = tid & 31;      // 8 rows x 32 cols per pass
    __shared__ uint16_t tl[32][33];            // [a-local][d-local], +1 pad
#pragma unroll
    for (int i = 0; i < 4; ++i) {
        int dl = r + i * 8;
        tl[c][dl] = f2bf_rne(Wp[(size_t)s * (D_ * A_) + (d0 + dl) * A_ + a0 + c]);
    }
    __syncthreads();
#pragma unroll
    for (int i = 0; i < 4; ++i) {
        int al = r + i * 8;
        wpt[(size_t)s * (A_ * D_) + (a0 + al) * D_ + d0 + c] = tl[al][c];
    }
}

// ---------------- kernel 2: FUSED projection + tanh/score + softmax + pool ----------------
// Block: 32 tokens, 256 threads (4 waves, 2x2). Full K=768 x-tile staged bf16 in LDS.
// All 3 scales' GEMMs run off the same staged tile (acc[3][4], 48 VGPRs).
// Epilogue: scr = sum_a v*tanh(proj+bp) -> windowed softmax (p=2,4,8 all inside
// the 32-token chunk) -> weighted pool from the LDS bf16 tile -> atomicAdd feats.
// x is read from HBM EXACTLY ONCE by the whole pipeline.
__global__ __launch_bounds__(256, 3)
void k_fused(const float* __restrict__ x, const uint16_t* __restrict__ wpt,
             const float* __restrict__ bp, const float* __restrict__ v,
             float* __restrict__ feats) {
    const int bt0  = blockIdx.x * 32;
    const int b    = bt0 >> 12;               // / T_
    const int tid  = threadIdx.x;
    const int lane = tid & 63;
    const int wave = tid >> 6;
    const int wrow = (wave >> 1) * 16;        // wave row offset (0/16)
    const int wcol = (wave & 1) * 64;         // wave col offset (0/64)
    const int l15  = lane & 15;
    const int quad = lane >> 4;

    __shared__ uint16_t xl[32][776];          // full-K bf16 x tile (+8 pad; 16B-aligned rows)
    __shared__ float    scrp[2][3][32];       // per-wave-col partial scores
    __shared__ float    wsm[3][32];           // softmax weights (x 1/W folded in)

    floatx4 acc[3][4];
#pragma unroll
    for (int s = 0; s < 3; ++s)
#pragma unroll
        for (int j = 0; j < 4; ++j) acc[s][j] = (floatx4){0.f, 0.f, 0.f, 0.f};

    // staging: 256 threads cover 32 rows x 64 cols per BK step (1 uint4 each)
    const int srow = tid >> 3;
    const int sc8  = (tid & 7) << 3;
    const float* gp0 = x + (size_t)(bt0 + srow) * D_ + sc8;

    for (int k0 = 0; k0 < D_; k0 += 64) {
        const float* gp = gp0 + k0;
        float4 f0 = *(const float4*)gp;
        float4 f1 = *(const float4*)(gp + 4);
        uint4 pk;
        pk.x = pack_bf16x2(f0.x, f0.y);
        pk.y = pack_bf16x2(f0.z, f0.w);
        pk.z = pack_bf16x2(f1.x, f1.y);
        pk.w = pack_bf16x2(f1.z, f1.w);
        *(uint4*)&xl[srow][k0 + sc8] = pk;    // disjoint columns per k0 -> one barrier/iter
        __syncthreads();

        short8 af[2];
        af[0] = *(const short8*)&xl[wrow + l15][k0 + quad * 8];
        af[1] = *(const short8*)&xl[wrow + l15][k0 + 32 + quad * 8];

#pragma unroll
        for (int s = 0; s < 3; ++s) {
            const uint16_t* wps = wpt + (size_t)s * (A_ * D_);
#pragma unroll
            for (int kk = 0; kk < 2; ++kk) {
#pragma unroll
                for (int j = 0; j < 4; ++j) {
                    short8 bf = *(const short8*)(wps + (size_t)(wcol + j * 16 + l15) * D_
                                                 + k0 + kk * 32 + quad * 8);
                    acc[s][j] = __builtin_amdgcn_mfma_f32_16x16x32_bf16(af[kk], bf, acc[s][j], 0, 0, 0);
                }
            }
        }
        // no trailing barrier: next iteration writes DIFFERENT LDS columns,
        // and its own __syncthreads orders write-before-read.
    }

    // ---- scr = sum_col v[col]*tanh(acc+bp[col]), reduced over the 16 lanes/quad ----
#pragma unroll
    for (int s = 0; s < 3; ++s) {
        float vj[4], bj[4];
#pragma unroll
        for (int j = 0; j < 4; ++j) {
            int col = wcol + j * 16 + l15;
            vj[j] = v[s * A_ + col];
            bj[j] = bp[s * A_ + col];
        }
        float rs[4] = {0.f, 0.f, 0.f, 0.f};
#pragma unroll
        for (int j = 0; j < 4; ++j)
#pragma unroll
            for (int r = 0; r < 4; ++r)
                rs[r] += vj[j] * fast_tanh(acc[s][j][r] + bj[j]);
#pragma unroll
        for (int r = 0; r < 4; ++r) {
            float t = rs[r];
            t += __shfl_xor(t, 1);
            t += __shfl_xor(t, 2);
            t += __shfl_xor(t, 4);
            t += __shfl_xor(t, 8);
            if (l15 == 0)
                scrp[wave & 1][s][wrow + quad * 4 + r] = t;
        }
    }
    __syncthreads();

    // ---- windowed softmax: 28 windows total (16 p=2, 8 p=4, 4 p=8) ----
    if (tid < 28) {
        int s, p, w0;
        if (tid < 16)      { s = 0; p = 2; w0 = tid * 2; }
        else if (tid < 24) { s = 1; p = 4; w0 = (tid - 16) * 4; }
        else               { s = 2; p = 8; w0 = (tid - 24) * 8; }
        float mx = -1e30f;
        for (int i = 0; i < p; ++i)
            mx = fmaxf(mx, scrp[0][s][w0 + i] + scrp[1][s][w0 + i]);
        float e[8]; float sum = 0.f;
        for (int i = 0; i < p; ++i) {
            e[i] = __expf(scrp[0][s][w0 + i] + scrp[1][s][w0 + i] - mx);
            sum += e[i];
        }
        float sc = ((float)p / (float)T_) / sum;   // softmax * 1/W
        for (int i = 0; i < p; ++i) wsm[s][w0 + i] = e[i] * sc;
    }
    __syncthreads();

    // ---- weighted pool from the LDS bf16 tile ----
    float pa[3][3];
#pragma unroll
    for (int s = 0; s < 3; ++s)
#pragma unroll
        for (int c = 0; c < 3; ++c) pa[s][c] = 0.f;
    for (int t = 0; t < 32; ++t) {
        float x0 = bf2f(xl[t][tid]);
        float x1 = bf2f(xl[t][tid + 256]);
        float x2 = bf2f(xl[t][tid + 512]);
        float w0 = wsm[0][t], w1 = wsm[1][t], w2 = wsm[2][t];
        pa[0][0] += w0 * x0; pa[0][1] += w0 * x1; pa[0][2] += w0 * x2;
        pa[1][0] += w1 * x0; pa[1][1] += w1 * x1; pa[1][2] += w1 * x2;
        pa[2][0] += w2 * x0; pa[2][1] += w2 * x1; pa[2][2] += w2 * x2;
    }
#pragma unroll
    for (int s = 0; s < 3; ++s)
#pragma unroll
        for (int c = 0; c < 3; ++c)
            atomicAdd(&feats[(size_t)(s * B_ + b) * D_ + tid + c * 256], pa[s][c]);
}

// ---------------- kernel 3: ms = feats_cat @ Wf (k-split, atomics) ----------------
__global__ __launch_bounds__(256)
void k_ms(const float* __restrict__ feats, const float* __restrict__ Wf,
          float* __restrict__ ms) {
    const int dchunk = blockIdx.x;   // 0..5  (128 cols each)
    const int kchunk = blockIdx.y;   // 0..31 (72 k each)
    const int k0  = kchunk * 72;
    const int tid = threadIdx.x;
    __shared__ float fl[32][72];     // feats_cat[b][k0+kk]

    for (int i = tid; i < 32 * 72; i += 256) {
        int bb = i / 72, kk = i - bb * 72;
        int k  = k0 + kk;
        int s  = k / D_;
        int d  = k - s * D_;
        fl[bb][kk] = feats[(size_t)(s * B_ + bb) * D_ + d];
    }
    __syncthreads();

    const int c     = dchunk * 128 + (tid & 127);
    const int brow0 = (tid >> 7) * 16;
    float acc[16];
#pragma unroll
    for (int r = 0; r < 16; ++r) acc[r] = 0.f;

    for (int kk = 0; kk < 72; ++kk) {
        float wv = Wf[(size_t)(k0 + kk) * D_ + c];
#pragma unroll
        for (int r = 0; r < 16; ++r) acc[r] += fl[brow0 + r][kk] * wv;
    }
#pragma unroll
    for (int r = 0; r < 16; ++r)
        atomicAdd(&ms[(size_t)(brow0 + r) * D_ + c], acc[r]);
}

// ---------------- kernel 4: bias + LayerNorm ----------------
__global__ __launch_bounds__(256)
void k_ln(const float* __restrict__ ms, const float* __restrict__ bf,
          const float* __restrict__ gamma, const float* __restrict__ beta,
          float* __restrict__ out) {
    const int b = blockIdx.x, tid = threadIdx.x;
    float vals[3]; float sum = 0.f, sq = 0.f;
#pragma unroll
    for (int c = 0; c < 3; ++c) {
        int d = tid + c * 256;
        float vv = ms[(size_t)b * D_ + d] + bf[d];
        vals[c] = vv; sum += vv; sq += vv * vv;
    }
#pragma unroll
    for (int m = 1; m < 64; m <<= 1) { sum += __shfl_xor(sum, m); sq += __shfl_xor(sq, m); }
    __shared__ float s1[4], s2[4];
    const int wave = tid >> 6;
    if ((tid & 63) == 0) { s1[wave] = sum; s2[wave] = sq; }
    __syncthreads();
    sum = s1[0] + s1[1] + s1[2] + s1[3];
    sq  = s2[0] + s2[1] + s2[2] + s2[3];
    float mu   = sum * (1.f / (float)D_);
    float var  = sq * (1.f / (float)D_) - mu * mu;
    float rstd = rsqrtf(var + LN_EPS);
#pragma unroll
    for (int c = 0; c < 3; ++c) {
        int d = tid + c * 256;
        out[(size_t)b * D_ + d] = (vals[c] - mu) * rstd * gamma[d] + beta[d];
    }
}

// ---------------- launcher ----------------
extern "C" void kernel_launch(void* const* d_in, const int* in_sizes, int n_in,
                              void* d_out, int out_size, void* d_ws, size_t ws_size,
                              hipStream_t stream) {
    const float* x     = (const float*)d_in[0];
    const float* Wp    = (const float*)d_in[1];
    const float* bp    = (const float*)d_in[2];
    const float* v     = (const float*)d_in[3];
    const float* Wf    = (const float*)d_in[4];
    const float* bfv   = (const float*)d_in[5];
    const float* gamma = (const float*)d_in[6];
    const float* beta  = (const float*)d_in[7];
    float* out = (float*)d_out;

    // ws layout (bytes):
    //   [0, 589824)           Wp^T bf16  (3*128*768 ushort)
    //   [589824, 884736)      feats fp32 (3*B*768)  -- atomically accumulated
    //   [884736, 983040)      ms fp32    (B*768)    -- atomically accumulated
    char* ws = (char*)d_ws;
    uint16_t* wpt   = (uint16_t*)ws;
    float*    feats = (float*)(ws + 589824);
    float*    ms    = (float*)(ws + 884736);

    hipMemsetAsync(feats, 0, 294912 + 98304, stream);     // zero feats + ms
    k_wp   <<<dim3(72, 4), 256, 0, stream>>>(Wp, wpt);
    k_fused<<<BT_ / 32, 256, 0, stream>>>(x, wpt, bp, v, feats);
    k_ms   <<<dim3(6, 32), 256, 0, stream>>>(feats, Wf, ms);
    k_ln   <<<B_, 256, 0, stream>>>(ms, bfv, gamma, beta, out);
}

// Round 3
// 769.376 us; speedup vs baseline: 1.3135x; 1.3135x over previous
//
#include <hip/hip_runtime.h>
#include <hip/hip_bf16.h>
#include <stdint.h>

// Problem constants (fixed by setup_inputs)
#define B_  32
#define T_  4096
#define D_  768
#define A_  128
#define BT_ (B_ * T_)          // 131072 tokens
#define LN_EPS 1e-5f

typedef __attribute__((ext_vector_type(8))) short  short8;   // 8 x bf16 (4 VGPRs)
typedef __attribute__((ext_vector_type(4))) float  floatx4;  // MFMA acc

// ---------------- helpers ----------------
__device__ __forceinline__ uint32_t pack_bf16x2(float a, float b) {
    __hip_bfloat162 h = __float22bfloat162_rn(make_float2(a, b));
    union { __hip_bfloat162 h; uint32_t u; } cv; cv.h = h;
    return cv.u;   // low 16 bits = a, high = b
}

__device__ __forceinline__ uint16_t f2bf_rne(float f) {
    union { float f; uint32_t u; } cv; cv.f = f;
    uint32_t u = cv.u;
    return (uint16_t)((u + 0x7FFFu + ((u >> 16) & 1u)) >> 16);
}

// fast tanh via exp:  tanh(x) = (e^{2x}-1)/(e^{2x}+1)
__device__ __forceinline__ float fast_tanh(float x) {
    float e = __expf(2.f * x);
    return __fdividef(e - 1.f, e + 1.f);
}

// ---------------- kernel 1: Wp -> Wp^T bf16 (tiled transpose) ----------------
// Wp: (3, 768, 128) fp32  ->  wpt: (3, 128, 768) bf16
__global__ __launch_bounds__(256)
void k_wp(const float* __restrict__ Wp, uint16_t* __restrict__ wpt) {
    const int sd = blockIdx.x;
    const int s  = sd / 24;
    const int d0 = (sd - s * 24) * 32;
    const int a0 = blockIdx.y * 32;
    const int tid = threadIdx.x;
    const int r = tid >> 5, c = tid & 31;
    __shared__ uint16_t tl[32][33];
#pragma unroll
    for (int i = 0; i < 4; ++i) {
        int dl = r + i * 8;
        tl[c][dl] = f2bf_rne(Wp[(size_t)s * (D_ * A_) + (d0 + dl) * A_ + a0 + c]);
    }
    __syncthreads();
#pragma unroll
    for (int i = 0; i < 4; ++i) {
        int al = r + i * 8;
        wpt[(size_t)s * (A_ * D_) + (a0 + al) * D_ + d0 + c] = tl[al][c];
    }
}

// ---------------- kernel 2: FUSED proj + tanh/score + softmax + pool ----------------
// M=128 tokens/block, 4 waves in 2x2 (wave row 0/64, wave col 0/64), N=128=A,
// all 3 scales accumulated simultaneously (acc[3][4][4] -> AGPRs).
// NO LDS staging, NO K-loop barriers: each lane gathers its A-fragment straight
// from global (16 rows x 128B per load-pair = full cache lines; waves 0/1 share
// rows -> L1 dedup) and packs fp32->bf16 in-register. B-fragments stream from
// the L2-resident 590 KB Wp^T, each feeding 4 MFMAs. The compiler is free to
// software-pipeline loads across iterations with fine-grained vmcnt (no
// s_barrier -> no vmcnt(0) drain).
// Epilogue: score reduce -> windowed softmax (p=2/4/8, 112 windows, all inside
// the 128-token tile) -> pool by re-reading the block's own (L2/L3-warm) x tile.
__global__ __launch_bounds__(256, 2)
void k_fused(const float* __restrict__ x, const uint16_t* __restrict__ wpt,
             const float* __restrict__ bp, const float* __restrict__ v,
             float* __restrict__ feats) {
    const int bt0  = blockIdx.x * 128;
    const int b    = bt0 >> 12;               // / T_
    const int tid  = threadIdx.x;
    const int lane = tid & 63;
    const int wave = tid >> 6;
    const int wrow = (wave >> 1) * 64;
    const int wcol = (wave & 1) * 64;
    const int l15  = lane & 15;
    const int quad = lane >> 4;

    __shared__ float scrp[2][3][128];
    __shared__ float wsm[3][128];

    floatx4 acc[3][4][4];
#pragma unroll
    for (int s = 0; s < 3; ++s)
#pragma unroll
        for (int i = 0; i < 4; ++i)
#pragma unroll
            for (int j = 0; j < 4; ++j) acc[s][i][j] = (floatx4){0.f, 0.f, 0.f, 0.f};

    // per-lane A row pointers (k advances by +k0)
    const float* xr[4];
#pragma unroll
    for (int i = 0; i < 4; ++i)
        xr[i] = x + (size_t)(bt0 + wrow + i * 16 + l15) * D_ + quad * 8;

    // per-lane B base pointers (col j adds j*16*D_, k advances by +k0)
    const uint16_t* wb[3];
#pragma unroll
    for (int s = 0; s < 3; ++s)
        wb[s] = wpt + (size_t)s * (A_ * D_) + (size_t)(wcol + l15) * D_ + quad * 8;

    for (int k0 = 0; k0 < D_; k0 += 32) {
        short8 af[4];
#pragma unroll
        for (int i = 0; i < 4; ++i) {
            float4 f0 = *(const float4*)(xr[i] + k0);
            float4 f1 = *(const float4*)(xr[i] + k0 + 4);
            union { short8 s8; uint32_t u[4]; } cv;
            cv.u[0] = pack_bf16x2(f0.x, f0.y);
            cv.u[1] = pack_bf16x2(f0.z, f0.w);
            cv.u[2] = pack_bf16x2(f1.x, f1.y);
            cv.u[3] = pack_bf16x2(f1.z, f1.w);
            af[i] = cv.s8;
        }
#pragma unroll
        for (int s = 0; s < 3; ++s) {
            short8 bf[4];
#pragma unroll
            for (int j = 0; j < 4; ++j)
                bf[j] = *(const short8*)(wb[s] + (size_t)j * (16 * D_) + k0);
#pragma unroll
            for (int j = 0; j < 4; ++j)
#pragma unroll
                for (int i = 0; i < 4; ++i)
                    acc[s][i][j] = __builtin_amdgcn_mfma_f32_16x16x32_bf16(
                        af[i], bf[j], acc[s][i][j], 0, 0, 0);
        }
    }

    // ---- scr = sum_col v[col]*tanh(acc+bp[col]); reduce 16 lanes/quad ----
#pragma unroll
    for (int s = 0; s < 3; ++s) {
        float vj[4], bj[4];
#pragma unroll
        for (int j = 0; j < 4; ++j) {
            int col = wcol + j * 16 + l15;
            vj[j] = v[s * A_ + col];
            bj[j] = bp[s * A_ + col];
        }
#pragma unroll
        for (int i = 0; i < 4; ++i) {
            float rs[4] = {0.f, 0.f, 0.f, 0.f};
#pragma unroll
            for (int j = 0; j < 4; ++j)
#pragma unroll
                for (int r = 0; r < 4; ++r)
                    rs[r] += vj[j] * fast_tanh(acc[s][i][j][r] + bj[j]);
#pragma unroll
            for (int r = 0; r < 4; ++r) {
                float t = rs[r];
                t += __shfl_xor(t, 1);
                t += __shfl_xor(t, 2);
                t += __shfl_xor(t, 4);
                t += __shfl_xor(t, 8);
                if (l15 == 0)
                    scrp[wave & 1][s][wrow + i * 16 + quad * 4 + r] = t;
            }
        }
    }
    __syncthreads();

    // ---- windowed softmax: 112 windows (64 p=2, 32 p=4, 16 p=8) ----
    if (tid < 112) {
        int s, p, w0;
        if (tid < 64)      { s = 0; p = 2; w0 = tid * 2; }
        else if (tid < 96) { s = 1; p = 4; w0 = (tid - 64) * 4; }
        else               { s = 2; p = 8; w0 = (tid - 96) * 8; }
        float mx = -1e30f;
        for (int i = 0; i < p; ++i)
            mx = fmaxf(mx, scrp[0][s][w0 + i] + scrp[1][s][w0 + i]);
        float e[8]; float sum = 0.f;
        for (int i = 0; i < p; ++i) {
            e[i] = __expf(scrp[0][s][w0 + i] + scrp[1][s][w0 + i] - mx);
            sum += e[i];
        }
        float sc = ((float)p / (float)T_) / sum;   // softmax * 1/W
        for (int i = 0; i < p; ++i) wsm[s][w0 + i] = e[i] * sc;
    }
    __syncthreads();

    // ---- weighted pool: re-read own x tile (cache-warm), fp32 ----
    float pa[3][3];
#pragma unroll
    for (int s = 0; s < 3; ++s)
#pragma unroll
        for (int c = 0; c < 3; ++c) pa[s][c] = 0.f;
    const float* xb = x + (size_t)bt0 * D_;
#pragma unroll 4
    for (int t = 0; t < 128; ++t) {
        float x0 = xb[t * D_ + tid];
        float x1 = xb[t * D_ + tid + 256];
        float x2 = xb[t * D_ + tid + 512];
        float w0 = wsm[0][t], w1 = wsm[1][t], w2 = wsm[2][t];
        pa[0][0] += w0 * x0; pa[0][1] += w0 * x1; pa[0][2] += w0 * x2;
        pa[1][0] += w1 * x0; pa[1][1] += w1 * x1; pa[1][2] += w1 * x2;
        pa[2][0] += w2 * x0; pa[2][1] += w2 * x1; pa[2][2] += w2 * x2;
    }
#pragma unroll
    for (int s = 0; s < 3; ++s)
#pragma unroll
        for (int c = 0; c < 3; ++c)
            atomicAdd(&feats[(size_t)(s * B_ + b) * D_ + tid + c * 256], pa[s][c]);
}

// ---------------- kernel 3: ms = feats_cat @ Wf (k-split, atomics) ----------------
__global__ __launch_bounds__(256)
void k_ms(const float* __restrict__ feats, const float* __restrict__ Wf,
          float* __restrict__ ms) {
    const int dchunk = blockIdx.x;   // 0..5  (128 cols each)
    const int kchunk = blockIdx.y;   // 0..31 (72 k each)
    const int k0  = kchunk * 72;
    const int tid = threadIdx.x;
    __shared__ float fl[32][72];

    for (int i = tid; i < 32 * 72; i += 256) {
        int bb = i / 72, kk = i - bb * 72;
        int k  = k0 + kk;
        int s  = k / D_;
        int d  = k - s * D_;
        fl[bb][kk] = feats[(size_t)(s * B_ + bb) * D_ + d];
    }
    __syncthreads();

    const int c     = dchunk * 128 + (tid & 127);
    const int brow0 = (tid >> 7) * 16;
    float acc[16];
#pragma unroll
    for (int r = 0; r < 16; ++r) acc[r] = 0.f;

    for (int kk = 0; kk < 72; ++kk) {
        float wv = Wf[(size_t)(k0 + kk) * D_ + c];
#pragma unroll
        for (int r = 0; r < 16; ++r) acc[r] += fl[brow0 + r][kk] * wv;
    }
#pragma unroll
    for (int r = 0; r < 16; ++r)
        atomicAdd(&ms[(size_t)(brow0 + r) * D_ + c], acc[r]);
}

// ---------------- kernel 4: bias + LayerNorm ----------------
__global__ __launch_bounds__(256)
void k_ln(const float* __restrict__ ms, const float* __restrict__ bf,
          const float* __restrict__ gamma, const float* __restrict__ beta,
          float* __restrict__ out) {
    const int b = blockIdx.x, tid = threadIdx.x;
    float vals[3]; float sum = 0.f, sq = 0.f;
#pragma unroll
    for (int c = 0; c < 3; ++c) {
        int d = tid + c * 256;
        float vv = ms[(size_t)b * D_ + d] + bf[d];
        vals[c] = vv; sum += vv; sq += vv * vv;
    }
#pragma unroll
    for (int m = 1; m < 64; m <<= 1) { sum += __shfl_xor(sum, m); sq += __shfl_xor(sq, m); }
    __shared__ float s1[4], s2[4];
    const int wave = tid >> 6;
    if ((tid & 63) == 0) { s1[wave] = sum; s2[wave] = sq; }
    __syncthreads();
    sum = s1[0] + s1[1] + s1[2] + s1[3];
    sq  = s2[0] + s2[1] + s2[2] + s2[3];
    float mu   = sum * (1.f / (float)D_);
    float var  = sq * (1.f / (float)D_) - mu * mu;
    float rstd = rsqrtf(var + LN_EPS);
#pragma unroll
    for (int c = 0; c < 3; ++c) {
        int d = tid + c * 256;
        out[(size_t)b * D_ + d] = (vals[c] - mu) * rstd * gamma[d] + beta[d];
    }
}

// ---------------- launcher ----------------
extern "C" void kernel_launch(void* const* d_in, const int* in_sizes, int n_in,
                              void* d_out, int out_size, void* d_ws, size_t ws_size,
                              hipStream_t stream) {
    const float* x     = (const float*)d_in[0];
    const float* Wp    = (const float*)d_in[1];
    const float* bp    = (const float*)d_in[2];
    const float* v     = (const float*)d_in[3];
    const float* Wf    = (const float*)d_in[4];
    const float* bfv   = (const float*)d_in[5];
    const float* gamma = (const float*)d_in[6];
    const float* beta  = (const float*)d_in[7];
    float* out = (float*)d_out;

    // ws layout (bytes):
    //   [0, 589824)           Wp^T bf16  (3*128*768 ushort)
    //   [589824, 884736)      feats fp32 (3*B*768)  -- atomically accumulated
    //   [884736, 983040)      ms fp32    (B*768)    -- atomically accumulated
    char* ws = (char*)d_ws;
    uint16_t* wpt   = (uint16_t*)ws;
    float*    feats = (float*)(ws + 589824);
    float*    ms    = (float*)(ws + 884736);

    hipMemsetAsync(feats, 0, 294912 + 98304, stream);     // zero feats + ms
    k_wp   <<<dim3(72, 4), 256, 0, stream>>>(Wp, wpt);
    k_fused<<<BT_ / 128, 256, 0, stream>>>(x, wpt, bp, v, feats);
    k_ms   <<<dim3(6, 32), 256, 0, stream>>>(feats, Wf, ms);
    k_ln   <<<B_, 256, 0, stream>>>(ms, bfv, gamma, beta, out);
}